// Round 1
// baseline (200.421 us; speedup 1.0000x reference)
//
#include <hip/hip_runtime.h>
#include <math.h>

#define BQ 128
#define NQ 256
#define SMAX 300
#define SPAD 304
#define CCLS 5
#define CCHG 3

// ---------------------------------------------------------------------------
// Pair kernel: grid = BQ*2 blocks of 256 threads.
//   blockIdx.x>>1 = batch b, &1 = phase (0: row mins over j, 1: col mins over i)
// Per block: build 15-entry class*charge NLL table per pflow j in LDS
// (stride 17 -> conflict-free both phases), then each lane scans the opposite
// side with wave-uniform (scalar-cached) loads of the loop side's data.
// ---------------------------------------------------------------------------
__global__ __launch_bounds__(256) void pair_kernel(
    const int* __restrict__ p_class, const int* __restrict__ p_charge,
    const float* __restrict__ cls_logits, const float* __restrict__ chg_logits,
    const float* __restrict__ p_pos, const float* __restrict__ pf_pos,
    const float* __restrict__ p_mom, const float* __restrict__ pf_mom,
    const float* __restrict__ p_en, const float* __restrict__ pf_en,
    float* __restrict__ out)
{
    const int b = blockIdx.x >> 1;
    const int phase = blockIdx.x & 1;
    const int t = threadIdx.x;

    __shared__ float s_tab[NQ * 17];   // [j][ci*3+chi], stride 17 (15 used)
    __shared__ float s_part[4];

    // ---- build pflow NLL table for j = t ----
    {
        const int gj = b * NQ + t;
        const float* cl = cls_logits + (size_t)gj * CCLS;
        float l0 = cl[0], l1 = cl[1], l2 = cl[2], l3 = cl[3], l4 = cl[4];
        float mx = fmaxf(fmaxf(fmaxf(l0, l1), fmaxf(l2, l3)), l4);
        float lse = mx + __logf(__expf(l0 - mx) + __expf(l1 - mx) + __expf(l2 - mx) +
                                __expf(l3 - mx) + __expf(l4 - mx));
        float nc[CCLS] = {lse - l0, lse - l1, lse - l2, lse - l3, lse - l4};

        const float* gl = chg_logits + (size_t)gj * CCHG;
        float g0 = gl[0], g1 = gl[1], g2 = gl[2];
        float gmx = fmaxf(fmaxf(g0, g1), g2);
        float glse = gmx + __logf(__expf(g0 - gmx) + __expf(g1 - gmx) + __expf(g2 - gmx));
        float ng[CCHG] = {glse - g0, glse - g1, glse - g2};

        float* row = &s_tab[t * 17];
        #pragma unroll
        for (int c = 0; c < CCLS; ++c)
            #pragma unroll
            for (int g = 0; g < CCHG; ++g)
                row[c * CCHG + g] = nc[c] + ng[g];
    }
    __syncthreads();

    float rmin = 3.0e38f;
    const int base = b * NQ;

    if (phase == 0) {
        // lane = particle i; loop over pflow j (uniform -> scalar loads)
        const int gi = base + t;
        const int cc = p_class[gi] * 3 + p_charge[gi];
        const float px = p_pos[gi * 3 + 0], py = p_pos[gi * 3 + 1], pz = p_pos[gi * 3 + 2];
        const float ax = p_mom[gi * 3 + 0], ay = p_mom[gi * 3 + 1], az = p_mom[gi * 3 + 2];
        const float pe = p_en[gi];
        #pragma unroll 4
        for (int j = 0; j < NQ; ++j) {
            const int gj = base + j;
            float dx = px - pf_pos[gj * 3 + 0];
            float dy = py - pf_pos[gj * 3 + 1];
            float dz = pz - pf_pos[gj * 3 + 2];
            float dp = sqrtf(dx * dx + dy * dy + dz * dz);
            float ex = ax - pf_mom[gj * 3 + 0];
            float ey = ay - pf_mom[gj * 3 + 1];
            float ez = az - pf_mom[gj * 3 + 2];
            float dm = sqrtf(ex * ex + ey * ey + ez * ez);
            float de = pe - pf_en[gj];
            float v = s_tab[j * 17 + cc] + dp + dm + de * de;
            rmin = fminf(rmin, v);
        }
    } else {
        // lane = pflow j; loop over particle i (uniform -> scalar loads)
        const int gj = base + t;
        const float qx = pf_pos[gj * 3 + 0], qy = pf_pos[gj * 3 + 1], qz = pf_pos[gj * 3 + 2];
        const float bx = pf_mom[gj * 3 + 0], by = pf_mom[gj * 3 + 1], bz = pf_mom[gj * 3 + 2];
        const float qe = pf_en[gj];
        const int tb = t * 17;
        #pragma unroll 4
        for (int i = 0; i < NQ; ++i) {
            const int gi = base + i;
            float dx = qx - p_pos[gi * 3 + 0];
            float dy = qy - p_pos[gi * 3 + 1];
            float dz = qz - p_pos[gi * 3 + 2];
            float dp = sqrtf(dx * dx + dy * dy + dz * dz);
            float ex = bx - p_mom[gi * 3 + 0];
            float ey = by - p_mom[gi * 3 + 1];
            float ez = bz - p_mom[gi * 3 + 2];
            float dm = sqrtf(ex * ex + ey * ey + ez * ez);
            float de = qe - p_en[gi];
            int cc = p_class[gi] * 3 + p_charge[gi];
            float v = s_tab[tb + cc] + dp + dm + de * de;
            rmin = fminf(rmin, v);
        }
    }

    // block sum of mins -> one atomic
    float v = rmin;
    #pragma unroll
    for (int off = 32; off > 0; off >>= 1) v += __shfl_down(v, off, 64);
    if ((t & 63) == 0) s_part[t >> 6] = v;
    __syncthreads();
    if (t == 0) {
        float s = s_part[0] + s_part[1] + s_part[2] + s_part[3];
        atomicAdd(out, s * (1.0f / BQ));
    }
}

// ---------------------------------------------------------------------------
// Column partial sums of predicted_setsizes: grid = BQ << log2n blocks,
// 320 threads (lane = column s). Writes ws[blk*SPAD + s].
// ---------------------------------------------------------------------------
__global__ __launch_bounds__(320) void colsum_kernel(
    const float* __restrict__ ss, float* __restrict__ ws, int log2n)
{
    const int blk = blockIdx.x;
    const int nchunk = 1 << log2n;
    const int b = blk >> log2n;
    const int ch = blk & (nchunk - 1);
    const int rows = NQ >> log2n;
    const int t = threadIdx.x;
    if (t >= SMAX) return;
    const float* base = ss + ((size_t)b * NQ + (size_t)ch * rows) * SMAX + t;
    float acc = 0.f;
    #pragma unroll 8
    for (int i = 0; i < rows; ++i) acc += base[(size_t)i * SMAX];
    ws[blk * SPAD + t] = acc;
}

// ---------------------------------------------------------------------------
// Set-size log-softmax NLL: grid = BQ blocks, 320 threads.
// nchunk > 0: combine ws partials; nchunk == 0: sum directly from global.
// ---------------------------------------------------------------------------
__global__ __launch_bounds__(320) void setsize_kernel(
    const float* __restrict__ ss, const float* __restrict__ ws,
    const int* __restrict__ n_particles, float* __restrict__ out, int nchunk)
{
    const int b = blockIdx.x;
    const int t = threadIdx.x;
    __shared__ float s_m[SMAX];
    __shared__ float s_part[5];
    __shared__ float s_red[1];

    float m = -3.0e38f;
    if (t < SMAX) {
        float acc = 0.f;
        if (nchunk > 0) {
            for (int c = 0; c < nchunk; ++c) acc += ws[(b * nchunk + c) * SPAD + t];
        } else {
            const float* base = ss + (size_t)b * NQ * SMAX + t;
            #pragma unroll 8
            for (int i = 0; i < NQ; ++i) acc += base[(size_t)i * SMAX];
        }
        m = acc * (1.0f / NQ);
        s_m[t] = m;
    }

    // block max
    float wm = m;
    #pragma unroll
    for (int off = 32; off > 0; off >>= 1) wm = fmaxf(wm, __shfl_down(wm, off, 64));
    const int wave = t >> 6, lane = t & 63;
    if (lane == 0) s_part[wave] = wm;
    __syncthreads();
    if (t == 0) {
        float mx = fmaxf(fmaxf(fmaxf(s_part[0], s_part[1]), fmaxf(s_part[2], s_part[3])),
                         s_part[4]);
        s_red[0] = mx;
    }
    __syncthreads();
    const float mx = s_red[0];

    // block sum of exp
    float e = (t < SMAX) ? __expf(m - mx) : 0.f;
    #pragma unroll
    for (int off = 32; off > 0; off >>= 1) e += __shfl_down(e, off, 64);
    if (lane == 0) s_part[wave] = e;
    __syncthreads();
    if (t == 0) {
        float s = s_part[0] + s_part[1] + s_part[2] + s_part[3] + s_part[4];
        int nb = n_particles[b];
        float loss = -(s_m[nb] - mx - __logf(s));
        atomicAdd(out, loss * (1.0f / BQ));
    }
}

extern "C" void kernel_launch(void* const* d_in, const int* in_sizes, int n_in,
                              void* d_out, int out_size, void* d_ws, size_t ws_size,
                              hipStream_t stream) {
    (void)in_sizes; (void)n_in;
    const int*   p_class     = (const int*)d_in[0];
    const int*   p_charge    = (const int*)d_in[1];
    const int*   n_particles = (const int*)d_in[2];
    const float* cls_logits  = (const float*)d_in[3];
    const float* chg_logits  = (const float*)d_in[4];
    const float* p_pos       = (const float*)d_in[5];
    const float* pf_pos      = (const float*)d_in[6];
    const float* p_mom       = (const float*)d_in[7];
    const float* pf_mom      = (const float*)d_in[8];
    const float* p_en        = (const float*)d_in[9];
    const float* pf_en       = (const float*)d_in[10];
    const float* setsizes    = (const float*)d_in[11];
    float* out = (float*)d_out;
    float* ws  = (float*)d_ws;

    // d_out is poisoned before every timed launch — zero it.
    hipMemsetAsync(out, 0, sizeof(float) * (size_t)out_size, stream);

    // pick the largest chunking that fits the workspace
    int log2n = -1;  // -1 => direct (no ws)
    if (ws_size >= (size_t)BQ * 8 * SPAD * sizeof(float))      log2n = 3;
    else if (ws_size >= (size_t)BQ * 4 * SPAD * sizeof(float)) log2n = 2;
    else if (ws_size >= (size_t)BQ * 2 * SPAD * sizeof(float)) log2n = 1;

    if (log2n >= 0) {
        colsum_kernel<<<BQ << log2n, 320, 0, stream>>>(setsizes, ws, log2n);
    }
    pair_kernel<<<BQ * 2, 256, 0, stream>>>(p_class, p_charge, cls_logits, chg_logits,
                                            p_pos, pf_pos, p_mom, pf_mom, p_en, pf_en, out);
    setsize_kernel<<<BQ, 320, 0, stream>>>(setsizes, ws, n_particles, out,
                                           log2n >= 0 ? (1 << log2n) : 0);
}

// Round 2
// 153.820 us; speedup vs baseline: 1.3030x; 1.3030x over previous
//
#include <hip/hip_runtime.h>
#include <math.h>

#define BQ 128
#define NQ 256
#define SMAX 300
#define SPAD 304
#define CCLS 5
#define CCHG 3

// ---------------------------------------------------------------------------
// Pair kernel: grid = BQ*2 blocks of 256 threads.
//   blockIdx.x>>1 = batch b, &1 = phase (0: lane=particle i, loop pflow j;
//                                        1: lane=pflow j, loop particle i)
// R2 change: ALL inner-loop data staged in LDS (R1 ran the loop off global
// loads -> 900 cyc/iter serial latency, 96 us). Packed s_pk[j][8] gives
// 2 uniform ds_read_b128 + 1 ds_read_b32 per iteration.
// ---------------------------------------------------------------------------
__global__ __launch_bounds__(256) void pair_kernel(
    const int* __restrict__ p_class, const int* __restrict__ p_charge,
    const float* __restrict__ cls_logits, const float* __restrict__ chg_logits,
    const float* __restrict__ p_pos, const float* __restrict__ pf_pos,
    const float* __restrict__ p_mom, const float* __restrict__ pf_mom,
    const float* __restrict__ p_en, const float* __restrict__ pf_en,
    float* __restrict__ out)
{
    const int b = blockIdx.x >> 1;
    const int phase = blockIdx.x & 1;
    const int t = threadIdx.x;
    const int base = b * NQ;
    const int gt = base + t;

    __shared__ float s_tab[NQ * 17];  // [j][ci*3+chi], stride 17
    __shared__ float s_pk[NQ * 8];    // packed loop-side: pos.xyz mom.xyz en cc
    __shared__ float s_part[4];

    // ---- build pflow NLL table for j = t (always from pflow logits) ----
    {
        const float* cl = cls_logits + (size_t)gt * CCLS;
        float l0 = cl[0], l1 = cl[1], l2 = cl[2], l3 = cl[3], l4 = cl[4];
        float mx = fmaxf(fmaxf(fmaxf(l0, l1), fmaxf(l2, l3)), l4);
        float lse = mx + __logf(__expf(l0 - mx) + __expf(l1 - mx) + __expf(l2 - mx) +
                                __expf(l3 - mx) + __expf(l4 - mx));
        float nc[CCLS] = {lse - l0, lse - l1, lse - l2, lse - l3, lse - l4};

        const float* gl = chg_logits + (size_t)gt * CCHG;
        float g0 = gl[0], g1 = gl[1], g2 = gl[2];
        float gmx = fmaxf(fmaxf(g0, g1), g2);
        float glse = gmx + __logf(__expf(g0 - gmx) + __expf(g1 - gmx) + __expf(g2 - gmx));
        float ng[CCHG] = {glse - g0, glse - g1, glse - g2};

        float* row = &s_tab[t * 17];
        #pragma unroll
        for (int c = 0; c < CCLS; ++c)
            #pragma unroll
            for (int g = 0; g < CCHG; ++g)
                row[c * CCHG + g] = nc[c] + ng[g];
    }

    // ---- stage loop-side packed data for index t ----
    {
        const float* pos = phase ? p_pos : pf_pos;
        const float* mom = phase ? p_mom : pf_mom;
        const float* en  = phase ? p_en  : pf_en;
        float* row = &s_pk[t * 8];
        row[0] = pos[gt * 3 + 0];
        row[1] = pos[gt * 3 + 1];
        row[2] = pos[gt * 3 + 2];
        row[3] = mom[gt * 3 + 0];
        row[4] = mom[gt * 3 + 1];
        row[5] = mom[gt * 3 + 2];
        row[6] = en[gt];
        row[7] = phase ? __int_as_float(p_class[gt] * 3 + p_charge[gt]) : 0.0f;
    }

    // ---- lane-side registers ----
    float lx, ly, lz, ma, mb, mc, le;
    int ccl = 0;
    if (phase == 0) {
        lx = p_pos[gt * 3 + 0]; ly = p_pos[gt * 3 + 1]; lz = p_pos[gt * 3 + 2];
        ma = p_mom[gt * 3 + 0]; mb = p_mom[gt * 3 + 1]; mc = p_mom[gt * 3 + 2];
        le = p_en[gt];
        ccl = p_class[gt] * 3 + p_charge[gt];
    } else {
        lx = pf_pos[gt * 3 + 0]; ly = pf_pos[gt * 3 + 1]; lz = pf_pos[gt * 3 + 2];
        ma = pf_mom[gt * 3 + 0]; mb = pf_mom[gt * 3 + 1]; mc = pf_mom[gt * 3 + 2];
        le = pf_en[gt];
    }
    __syncthreads();

    float rmin = 3.0e38f;

    if (phase == 0) {
        // table index = j*17 + ccl : <=15 consecutive words -> conflict-free
        #pragma unroll 8
        for (int j = 0; j < NQ; ++j) {
            const float4 u = *(const float4*)&s_pk[j * 8];
            const float4 w = *(const float4*)&s_pk[j * 8 + 4];
            float dx = lx - u.x, dy = ly - u.y, dz = lz - u.z;
            float dp = sqrtf(dx * dx + dy * dy + dz * dz);
            float ex = ma - u.w, ey = mb - w.x, ez = mc - w.y;
            float dm = sqrtf(ex * ex + ey * ey + ez * ez);
            float de = le - w.z;
            float v = s_tab[j * 17 + ccl] + dp + dm + de * de;
            rmin = fminf(rmin, v);
        }
    } else {
        // table index = t*17 + cc(i) : stride-17 per-lane -> 2-way, free
        const int tb = t * 17;
        #pragma unroll 8
        for (int i = 0; i < NQ; ++i) {
            const float4 u = *(const float4*)&s_pk[i * 8];
            const float4 w = *(const float4*)&s_pk[i * 8 + 4];
            float dx = lx - u.x, dy = ly - u.y, dz = lz - u.z;
            float dp = sqrtf(dx * dx + dy * dy + dz * dz);
            float ex = ma - u.w, ey = mb - w.x, ez = mc - w.y;
            float dm = sqrtf(ex * ex + ey * ey + ez * ez);
            float de = le - w.z;
            float v = s_tab[tb + __float_as_int(w.w)] + dp + dm + de * de;
            rmin = fminf(rmin, v);
        }
    }

    // block sum of mins -> one atomic
    float v = rmin;
    #pragma unroll
    for (int off = 32; off > 0; off >>= 1) v += __shfl_down(v, off, 64);
    if ((t & 63) == 0) s_part[t >> 6] = v;
    __syncthreads();
    if (t == 0) {
        float s = s_part[0] + s_part[1] + s_part[2] + s_part[3];
        atomicAdd(out, s * (1.0f / BQ));
    }
}

// ---------------------------------------------------------------------------
// Column partial sums of predicted_setsizes: grid = BQ << log2n blocks,
// 320 threads (lane = column s). Writes ws[blk*SPAD + s].
// ---------------------------------------------------------------------------
__global__ __launch_bounds__(320) void colsum_kernel(
    const float* __restrict__ ss, float* __restrict__ ws, int log2n)
{
    const int blk = blockIdx.x;
    const int nchunk = 1 << log2n;
    const int b = blk >> log2n;
    const int ch = blk & (nchunk - 1);
    const int rows = NQ >> log2n;
    const int t = threadIdx.x;
    if (t >= SMAX) return;
    const float* base = ss + ((size_t)b * NQ + (size_t)ch * rows) * SMAX + t;
    float acc = 0.f;
    #pragma unroll 8
    for (int i = 0; i < rows; ++i) acc += base[(size_t)i * SMAX];
    ws[blk * SPAD + t] = acc;
}

// ---------------------------------------------------------------------------
// Set-size log-softmax NLL: grid = BQ blocks, 320 threads.
// nchunk > 0: combine ws partials; nchunk == 0: sum directly from global.
// ---------------------------------------------------------------------------
__global__ __launch_bounds__(320) void setsize_kernel(
    const float* __restrict__ ss, const float* __restrict__ ws,
    const int* __restrict__ n_particles, float* __restrict__ out, int nchunk)
{
    const int b = blockIdx.x;
    const int t = threadIdx.x;
    __shared__ float s_m[SMAX];
    __shared__ float s_part[5];
    __shared__ float s_red[1];

    float m = -3.0e38f;
    if (t < SMAX) {
        float acc = 0.f;
        if (nchunk > 0) {
            for (int c = 0; c < nchunk; ++c) acc += ws[(b * nchunk + c) * SPAD + t];
        } else {
            const float* base = ss + (size_t)b * NQ * SMAX + t;
            #pragma unroll 8
            for (int i = 0; i < NQ; ++i) acc += base[(size_t)i * SMAX];
        }
        m = acc * (1.0f / NQ);
        s_m[t] = m;
    }

    // block max
    float wm = m;
    #pragma unroll
    for (int off = 32; off > 0; off >>= 1) wm = fmaxf(wm, __shfl_down(wm, off, 64));
    const int wave = t >> 6, lane = t & 63;
    if (lane == 0) s_part[wave] = wm;
    __syncthreads();
    if (t == 0) {
        float mx = fmaxf(fmaxf(fmaxf(s_part[0], s_part[1]), fmaxf(s_part[2], s_part[3])),
                         s_part[4]);
        s_red[0] = mx;
    }
    __syncthreads();
    const float mx = s_red[0];

    // block sum of exp
    float e = (t < SMAX) ? __expf(m - mx) : 0.f;
    #pragma unroll
    for (int off = 32; off > 0; off >>= 1) e += __shfl_down(e, off, 64);
    if (lane == 0) s_part[wave] = e;
    __syncthreads();
    if (t == 0) {
        float s = s_part[0] + s_part[1] + s_part[2] + s_part[3] + s_part[4];
        int nb = n_particles[b];
        float loss = -(s_m[nb] - mx - __logf(s));
        atomicAdd(out, loss * (1.0f / BQ));
    }
}

extern "C" void kernel_launch(void* const* d_in, const int* in_sizes, int n_in,
                              void* d_out, int out_size, void* d_ws, size_t ws_size,
                              hipStream_t stream) {
    (void)in_sizes; (void)n_in;
    const int*   p_class     = (const int*)d_in[0];
    const int*   p_charge    = (const int*)d_in[1];
    const int*   n_particles = (const int*)d_in[2];
    const float* cls_logits  = (const float*)d_in[3];
    const float* chg_logits  = (const float*)d_in[4];
    const float* p_pos       = (const float*)d_in[5];
    const float* pf_pos      = (const float*)d_in[6];
    const float* p_mom       = (const float*)d_in[7];
    const float* pf_mom      = (const float*)d_in[8];
    const float* p_en        = (const float*)d_in[9];
    const float* pf_en       = (const float*)d_in[10];
    const float* setsizes    = (const float*)d_in[11];
    float* out = (float*)d_out;
    float* ws  = (float*)d_ws;

    // d_out is poisoned before every timed launch — zero it.
    hipMemsetAsync(out, 0, sizeof(float) * (size_t)out_size, stream);

    // pick the largest chunking that fits the workspace
    int log2n = -1;  // -1 => direct (no ws)
    if (ws_size >= (size_t)BQ * 8 * SPAD * sizeof(float))      log2n = 3;
    else if (ws_size >= (size_t)BQ * 4 * SPAD * sizeof(float)) log2n = 2;
    else if (ws_size >= (size_t)BQ * 2 * SPAD * sizeof(float)) log2n = 1;

    if (log2n >= 0) {
        colsum_kernel<<<BQ << log2n, 320, 0, stream>>>(setsizes, ws, log2n);
    }
    pair_kernel<<<BQ * 2, 256, 0, stream>>>(p_class, p_charge, cls_logits, chg_logits,
                                            p_pos, pf_pos, p_mom, pf_mom, p_en, pf_en, out);
    setsize_kernel<<<BQ, 320, 0, stream>>>(setsizes, ws, n_particles, out,
                                           log2n >= 0 ? (1 << log2n) : 0);
}

// Round 4
// 117.483 us; speedup vs baseline: 1.7060x; 1.3093x over previous
//
#include <hip/hip_runtime.h>
#include <math.h>

#define BQ 128
#define NQ 256
#define SMAX 300
#define CCLS 5
#define CCHG 3
#define TSTR 268          // s_tabT row stride (floats), cc-major [15][268]
#define RSTR 12           // s_rows row stride (floats) — 48B keeps b128 align, 2-way banks
#define INFV 3.0e38f

#define NPAIRBLK 512      // 128 batches * 2 dirs * 2 row-halves
#define NTHREADS 512

// single-instruction v_sqrt_f32 (|rel err| ~1ulp-ish — fine vs 42.88 abs tol)
__device__ __forceinline__ float fast_sqrtf(float x) {
    return __builtin_amdgcn_sqrtf(x);
}

// shared layout (floats):
//  s_tabT : [0,4020)       15*268
//  s_cols : [4020,6068)    256*8  (pos.xyz mom.xyz en cc)
//  s_rows : [6068,7604)    128*12 (words 0..7 used)
//  s_part : [7604,7636)
// aliases after barrier: s_red(16*128) over s_tabT; setsize uses [0,1k).
#define SMEM_FLOATS 7636

__global__ __launch_bounds__(NTHREADS) void fused_kernel(
    const int* __restrict__ p_class, const int* __restrict__ p_charge,
    const int* __restrict__ n_particles,
    const float* __restrict__ cls_logits, const float* __restrict__ chg_logits,
    const float* __restrict__ p_pos, const float* __restrict__ pf_pos,
    const float* __restrict__ p_mom, const float* __restrict__ pf_mom,
    const float* __restrict__ p_en, const float* __restrict__ pf_en,
    const float* __restrict__ setsizes, float* __restrict__ out)
{
    __shared__ float smem[SMEM_FLOATS];
    const int t = threadIdx.x;
    const int blk = blockIdx.x;

    if (blk < NPAIRBLK) {
        // ---------------- pair-matrix block ----------------
        const int b   = blk >> 2;
        const int dir = (blk >> 1) & 1;   // 0: rows=particles (particle_loss), 1: rows=pflow (pflow_loss)
        const int rh  = blk & 1;          // row half
        const int base = b * NQ;
        float* s_tabT = smem;
        float* s_cols = smem + 4020;
        float* s_rows = smem + 6068;
        float* s_part = smem + 7604;

        // ---- stage: threads 0..255 build NLL table row t + col-side row t ----
        if (t < NQ) {
            const int gj = base + t;
            const float* cl = cls_logits + (size_t)gj * CCLS;
            float l0=cl[0], l1=cl[1], l2=cl[2], l3=cl[3], l4=cl[4];
            float mx = fmaxf(fmaxf(fmaxf(l0,l1),fmaxf(l2,l3)),l4);
            float lse = mx + __logf(__expf(l0-mx)+__expf(l1-mx)+__expf(l2-mx)+
                                    __expf(l3-mx)+__expf(l4-mx));
            const float* gl = chg_logits + (size_t)gj * CCHG;
            float g0=gl[0], g1=gl[1], g2=gl[2];
            float gmx = fmaxf(fmaxf(g0,g1),g2);
            float glse = gmx + __logf(__expf(g0-gmx)+__expf(g1-gmx)+__expf(g2-gmx));
            float nc[CCLS] = {lse-l0, lse-l1, lse-l2, lse-l3, lse-l4};
            float ng[CCHG] = {glse-g0, glse-g1, glse-g2};
            #pragma unroll
            for (int c = 0; c < CCLS; ++c)
                #pragma unroll
                for (int g = 0; g < CCHG; ++g)
                    s_tabT[(c*CCHG+g)*TSTR + t] = nc[c] + ng[g];

            const float* cpos = dir ? p_pos : pf_pos;
            const float* cmom = dir ? p_mom : pf_mom;
            const float* cen  = dir ? p_en  : pf_en;
            float* cr = &s_cols[t*8];
            cr[0]=cpos[gj*3+0]; cr[1]=cpos[gj*3+1]; cr[2]=cpos[gj*3+2];
            cr[3]=cmom[gj*3+0]; cr[4]=cmom[gj*3+1]; cr[5]=cmom[gj*3+2];
            cr[6]=cen[gj];
            cr[7]= dir ? __int_as_float(p_class[gj]*CCHG + p_charge[gj]) : 0.0f;
        } else if (t < NQ + 128) {
            const int rr = t - NQ;
            const int gr = base + rh*128 + rr;
            const float* rpos = dir ? pf_pos : p_pos;
            const float* rmom = dir ? pf_mom : p_mom;
            const float* ren  = dir ? pf_en  : p_en;
            float* rw = &s_rows[rr*RSTR];
            rw[0]=rpos[gr*3+0]; rw[1]=rpos[gr*3+1]; rw[2]=rpos[gr*3+2];
            rw[3]=rmom[gr*3+0]; rw[4]=rmom[gr*3+1]; rw[5]=rmom[gr*3+2];
            rw[6]=ren[gr];
            rw[7]= dir ? 0.0f : __int_as_float(p_class[gr]*CCHG + p_charge[gr]);
        }
        __syncthreads();

        const int tx = t & 31;   // rows: tx + 32*r, r in [0,4)
        const int ty = t >> 5;   // cols: ty*16 + [0,16)
        const int c0 = ty * 16;

        float4 ra[4], rb[4];
        int ccr[4];
        #pragma unroll
        for (int r = 0; r < 4; ++r) {
            const int rr = tx + 32*r;
            ra[r] = *(const float4*)&s_rows[rr*RSTR];
            rb[r] = *(const float4*)&s_rows[rr*RSTR + 4];
            ccr[r] = __float_as_int(rb[r].w) * TSTR;
        }
        float rmin[4] = {INFV, INFV, INFV, INFV};

        if (dir == 0) {
            // tab: per row, 4 consecutive-j b128 reads (cc-major layout)
            #pragma unroll
            for (int cs = 0; cs < 4; ++cs) {
                float4 tb[4];
                #pragma unroll
                for (int r = 0; r < 4; ++r)
                    tb[r] = *(const float4*)&s_tabT[ccr[r] + c0 + cs*4];
                #pragma unroll
                for (int c = 0; c < 4; ++c) {
                    const int j = c0 + cs*4 + c;
                    const float4 cd0 = *(const float4*)&s_cols[j*8];
                    const float4 cd1 = *(const float4*)&s_cols[j*8+4];
                    #pragma unroll
                    for (int r = 0; r < 4; ++r) {
                        float dx=ra[r].x-cd0.x, dy=ra[r].y-cd0.y, dz=ra[r].z-cd0.z;
                        float ex=ra[r].w-cd0.w, ey=rb[r].x-cd1.x, ez=rb[r].y-cd1.y;
                        float de=rb[r].z-cd1.z;
                        float v = ((const float*)&tb[r])[c]
                                + fast_sqrtf(dx*dx + dy*dy + dz*dz)
                                + fast_sqrtf(ex*ex + ey*ey + ez*ez)
                                + de*de;
                        rmin[r] = fminf(rmin[r], v);
                    }
                }
            }
        } else {
            // rows are pflow j; tab indexed [cc_col][j_row] — consecutive-lane b32
            #pragma unroll
            for (int c16 = 0; c16 < 16; ++c16) {
                const int i = c0 + c16;
                const float4 cd0 = *(const float4*)&s_cols[i*8];
                const float4 cd1 = *(const float4*)&s_cols[i*8+4];
                const float* tabp = &s_tabT[__float_as_int(cd1.w)*TSTR + rh*128 + tx];
                #pragma unroll
                for (int r = 0; r < 4; ++r) {
                    float dx=ra[r].x-cd0.x, dy=ra[r].y-cd0.y, dz=ra[r].z-cd0.z;
                    float ex=ra[r].w-cd0.w, ey=rb[r].x-cd1.x, ez=rb[r].y-cd1.y;
                    float de=rb[r].z-cd1.z;
                    float v = tabp[32*r]
                            + fast_sqrtf(dx*dx + dy*dy + dz*dz)
                            + fast_sqrtf(ex*ex + ey*ey + ez*ez)
                            + de*de;
                    rmin[r] = fminf(rmin[r], v);
                }
            }
        }

        __syncthreads();                 // all tab reads done -> safe to overlay
        float* s_red = smem;             // [16][128] over s_tabT
        #pragma unroll
        for (int r = 0; r < 4; ++r)
            s_red[ty*128 + tx + 32*r] = rmin[r];
        __syncthreads();
        if (t < 128) {
            float m = s_red[t];
            #pragma unroll
            for (int k = 1; k < 16; ++k) m = fminf(m, s_red[k*128 + t]);
            #pragma unroll
            for (int off = 32; off > 0; off >>= 1) m += __shfl_down(m, off);
            if ((t & 63) == 0) s_part[t >> 6] = m;
        }
        __syncthreads();
        if (t == 0) atomicAdd(out, (s_part[0] + s_part[1]) * (1.0f / BQ));

    } else {
        // ---------------- set-size block (one per batch) ----------------
        const int b = blk - NPAIRBLK;
        float* s_ss = smem;          // [2][304]
        float* s_m  = smem + 608;    // [304]
        float* s_p5 = smem + 912;    // [8]
        float* s_one= smem + 920;

        const int slice = t >> 8;    // 0/1 -> rows slice*128..+128
        const int col = t & 255;
        const float* bp = setsizes + (size_t)b * NQ * SMAX + (size_t)(slice*128) * SMAX;
        {
            const float* p = bp + col;
            float acc = 0.f;
            #pragma unroll 8
            for (int i = 0; i < 128; ++i) acc += p[(size_t)i * SMAX];
            s_ss[slice*304 + col] = acc;
        }
        if (col < SMAX - NQ) {       // cols 256..299
            const float* p = bp + (NQ + col);
            float acc = 0.f;
            #pragma unroll 8
            for (int i = 0; i < 128; ++i) acc += p[(size_t)i * SMAX];
            s_ss[slice*304 + NQ + col] = acc;
        }
        __syncthreads();
        float m = -INFV;
        if (t < SMAX) { m = (s_ss[t] + s_ss[304 + t]) * (1.0f / NQ); s_m[t] = m; }
        const int wave = t >> 6, lane = t & 63;
        float wm = m;
        #pragma unroll
        for (int off = 32; off > 0; off >>= 1) wm = fmaxf(wm, __shfl_down(wm, off));
        if (lane == 0 && wave < 5) s_p5[wave] = wm;
        __syncthreads();
        if (t == 0)
            s_one[0] = fmaxf(fmaxf(fmaxf(s_p5[0], s_p5[1]), fmaxf(s_p5[2], s_p5[3])), s_p5[4]);
        __syncthreads();
        const float mx = s_one[0];
        float e = (t < SMAX) ? __expf(m - mx) : 0.f;
        #pragma unroll
        for (int off = 32; off > 0; off >>= 1) e += __shfl_down(e, off);
        if (lane == 0 && wave < 5) s_p5[wave] = e;
        __syncthreads();
        if (t == 0) {
            float s = s_p5[0] + s_p5[1] + s_p5[2] + s_p5[3] + s_p5[4];
            int nb = n_particles[b];
            float loss = -(s_m[nb] - mx - __logf(s));
            atomicAdd(out, loss * (1.0f / BQ));
        }
    }
}

extern "C" void kernel_launch(void* const* d_in, const int* in_sizes, int n_in,
                              void* d_out, int out_size, void* d_ws, size_t ws_size,
                              hipStream_t stream) {
    (void)in_sizes; (void)n_in; (void)d_ws; (void)ws_size;
    const int*   p_class     = (const int*)d_in[0];
    const int*   p_charge    = (const int*)d_in[1];
    const int*   n_particles = (const int*)d_in[2];
    const float* cls_logits  = (const float*)d_in[3];
    const float* chg_logits  = (const float*)d_in[4];
    const float* p_pos       = (const float*)d_in[5];
    const float* pf_pos      = (const float*)d_in[6];
    const float* p_mom       = (const float*)d_in[7];
    const float* pf_mom      = (const float*)d_in[8];
    const float* p_en        = (const float*)d_in[9];
    const float* pf_en       = (const float*)d_in[10];
    const float* setsizes    = (const float*)d_in[11];
    float* out = (float*)d_out;

    (void)hipMemsetAsync(out, 0, sizeof(float) * (size_t)out_size, stream);

    fused_kernel<<<NPAIRBLK + BQ, NTHREADS, 0, stream>>>(
        p_class, p_charge, n_particles, cls_logits, chg_logits,
        p_pos, pf_pos, p_mom, pf_mom, p_en, pf_en, setsizes, out);
}